// Round 1
// baseline (109.615 us; speedup 1.0000x reference)
//
#include <hip/hip_runtime.h>
#include <math.h>

#define BB 512
#define DD 256
#define TMARGIN 0.2f

// ---------------- Kernel 1: per-row squared norms ----------------
// grid=512 blocks x 64 threads (one wave per row)
__global__ void tl_norms(const float* __restrict__ X, float* __restrict__ norms) {
    int row = blockIdx.x;
    int lane = threadIdx.x;             // 0..63
    const float4* xr = (const float4*)(X + row * DD);
    float4 a = xr[lane];                // 64 lanes * 4 = 256 cols
    float s = a.x * a.x + a.y * a.y + a.z * a.z + a.w * a.w;
    #pragma unroll
    for (int o = 32; o > 0; o >>= 1) s += __shfl_xor(s, o, 64);
    if (lane == 0) norms[row] = s;
}

// ---------------- Kernel 2: per-anchor triplet accumulation ----------------
// grid=512 blocks (one per anchor) x 256 threads
__global__ void tl_triplet(const float* __restrict__ X,
                           const int* __restrict__ labels,
                           const float* __restrict__ norms,
                           float* __restrict__ total,
                           unsigned int* __restrict__ count) {
    __shared__ float xi[DD];
    __shared__ float drow[BB];
    __shared__ int   lab[BB];
    __shared__ float redf[4];
    __shared__ unsigned int redc[4];

    const int i    = blockIdx.x;
    const int tid  = threadIdx.x;       // 0..255
    const int lane = tid & 63;
    const int wave = tid >> 6;          // 0..3

    // stage anchor row + labels in LDS
    if (tid < 64) ((float4*)xi)[tid] = ((const float4*)(X + i * DD))[tid];
    lab[tid]       = labels[tid];
    lab[tid + 256] = labels[tid + 256];
    __syncthreads();

    const float ni = norms[i];
    const float4 a = ((const float4*)xi)[lane];

    // Phase 1: d_row[j] = sqrt(max(n_i + n_j - 2*dot(x_i, x_j), 0))
    for (int j = wave; j < BB; j += 4) {
        const float4 b = ((const float4*)(X + j * DD))[lane];
        float s = a.x * b.x + a.y * b.y + a.z * b.z + a.w * b.w;
        #pragma unroll
        for (int o = 32; o > 0; o >>= 1) s += __shfl_xor(s, o, 64);
        if (lane == 0) {
            float sq = ni + norms[j] - 2.0f * s;
            drow[j] = (sq > 0.0f) ? sqrtf(sq) : 0.0f;
        }
    }
    __syncthreads();

    // Phase 2: each thread owns negatives k = tid and tid+256
    const int li = lab[i];
    const float dk0 = drow[tid];
    const float dk1 = drow[tid + 256];
    const bool  n0  = (lab[tid] != li);
    const bool  n1  = (lab[tid + 256] != li);
    const unsigned int cpp = (n0 ? 1u : 0u) + (n1 ? 1u : 0u);

    float acc = 0.0f;
    unsigned int cnt = 0;
    for (int j = 0; j < BB; ++j) {
        if (lab[j] == li && j != i) {       // valid positive (uniform branch)
            const float dj = drow[j];
            if (n0) { float v = dj - dk0 + TMARGIN; acc += (v > 0.0f) ? v : 0.0f; }
            if (n1) { float v = dj - dk1 + TMARGIN; acc += (v > 0.0f) ? v : 0.0f; }
            cnt += cpp;
        }
    }

    // block reduction
    #pragma unroll
    for (int o = 32; o > 0; o >>= 1) {
        acc += __shfl_xor(acc, o, 64);
        cnt += __shfl_xor(cnt, o, 64);
    }
    if (lane == 0) { redf[wave] = acc; redc[wave] = cnt; }
    __syncthreads();
    if (tid == 0) {
        float af = redf[0] + redf[1] + redf[2] + redf[3];
        unsigned int cf = redc[0] + redc[1] + redc[2] + redc[3];
        atomicAdd(total, af);
        atomicAdd(count, cf);
    }
}

// ---------------- Kernel 3: finalize ----------------
__global__ void tl_finalize(const float* __restrict__ total,
                            const unsigned int* __restrict__ count,
                            float* __restrict__ out) {
    unsigned int c = *count;
    out[0] = (c > 0u) ? (*total / (float)c) : 0.0f;
}

extern "C" void kernel_launch(void* const* d_in, const int* in_sizes, int n_in,
                              void* d_out, int out_size, void* d_ws, size_t ws_size,
                              hipStream_t stream) {
    const float* X      = (const float*)d_in[0];   // [512,256] f32
    const int*   labels = (const int*)d_in[1];     // [512] int

    float*        norms = (float*)d_ws;                           // 512 floats
    float*        total = (float*)((char*)d_ws + 2048);           // 1 float
    unsigned int* count = (unsigned int*)((char*)d_ws + 2052);    // 1 uint

    // zero the accumulators every call (workspace is poisoned once, never re-poisoned)
    hipMemsetAsync((char*)d_ws + 2048, 0, 8, stream);

    tl_norms<<<BB, 64, 0, stream>>>(X, norms);
    tl_triplet<<<BB, 256, 0, stream>>>(X, labels, norms, total, count);
    tl_finalize<<<1, 1, 0, stream>>>(total, count, (float*)d_out);
}

// Round 2
// 39.463 us; speedup vs baseline: 2.7777x; 2.7777x over previous
//
#include <hip/hip_runtime.h>
#include <math.h>

#define BB 512
#define DD 256
#define TMARGIN 0.2f

// ---------------- Kernel 0: transpose X[512][256] -> XT[256][512] ----------------
// grid (8,4), block 256
__global__ void tl_transpose(const float* __restrict__ X, float* __restrict__ XT) {
    __shared__ float tile[64][65];
    const int t  = threadIdx.x;
    const int tx = t & 63, ty = t >> 6;       // ty 0..3
    const int r0 = blockIdx.x * 64;           // row tile of X (8 tiles)
    const int c0 = blockIdx.y * 64;           // col tile of X (4 tiles)
    #pragma unroll
    for (int r = ty; r < 64; r += 4)
        tile[r][tx] = X[(r0 + r) * DD + c0 + tx];
    __syncthreads();
    #pragma unroll
    for (int r = ty; r < 64; r += 4)
        XT[(c0 + r) * BB + r0 + tx] = tile[tx][r];
}

// ---------------- Kernel 1: per-row squared norms ----------------
// grid 512 x 64 threads (one wave per row)
__global__ void tl_norms(const float* __restrict__ X, float* __restrict__ norms) {
    int row = blockIdx.x;
    int lane = threadIdx.x;
    const float4* xr = (const float4*)(X + row * DD);
    float4 a = xr[lane];
    float s = a.x * a.x + a.y * a.y + a.z * a.z + a.w * a.w;
    #pragma unroll
    for (int o = 32; o > 0; o >>= 1) s += __shfl_xor(s, o, 64);
    if (lane == 0) norms[row] = s;
}

// ---------------- Kernel 2: fused distance + triplet, 4 anchors per block ----------------
// grid 128, block 256
__global__ void tl_main(const float* __restrict__ X,
                        const float* __restrict__ XT,
                        const int* __restrict__ labels,
                        const float* __restrict__ norms,
                        float* __restrict__ total,
                        unsigned int* __restrict__ count) {
    __shared__ float xi[4][DD];        // 4 anchor rows
    __shared__ float drow[4][BB];      // 4 distance rows
    __shared__ int   lab[BB];
    __shared__ int   plist[4][BB];     // positive index lists
    __shared__ int   pcnt[4];
    __shared__ float partf[4];

    const int t  = threadIdx.x;        // 0..255
    const int i0 = blockIdx.x * 4;

    // stage 4 anchor rows (coalesced float4) + labels
    {
        int r = t >> 6, c = t & 63;
        ((float4*)xi[r])[c] = ((const float4*)(X + (size_t)(i0 + r) * DD))[c];
    }
    lab[t]       = labels[t];
    lab[t + 256] = labels[t + 256];
    if (t < 4) pcnt[t] = 0;
    __syncthreads();

    // ---- phase 1: 8 dot products per thread (4 anchors x 2 columns) ----
    float a00 = 0.f, a01 = 0.f, a10 = 0.f, a11 = 0.f;
    float a20 = 0.f, a21 = 0.f, a30 = 0.f, a31 = 0.f;
    const float2* XT2 = (const float2*)XT;
    for (int g = 0; g < DD / 4; ++g) {
        const int d = g * 4;
        float4 x0 = ((const float4*)xi[0])[g];
        float4 x1 = ((const float4*)xi[1])[g];
        float4 x2 = ((const float4*)xi[2])[g];
        float4 x3 = ((const float4*)xi[3])[g];
        float2 b0 = XT2[(size_t)(d + 0) * (BB / 2) + t];
        float2 b1 = XT2[(size_t)(d + 1) * (BB / 2) + t];
        float2 b2 = XT2[(size_t)(d + 2) * (BB / 2) + t];
        float2 b3 = XT2[(size_t)(d + 3) * (BB / 2) + t];
        a00 += x0.x * b0.x; a01 += x0.x * b0.y;
        a10 += x1.x * b0.x; a11 += x1.x * b0.y;
        a20 += x2.x * b0.x; a21 += x2.x * b0.y;
        a30 += x3.x * b0.x; a31 += x3.x * b0.y;
        a00 += x0.y * b1.x; a01 += x0.y * b1.y;
        a10 += x1.y * b1.x; a11 += x1.y * b1.y;
        a20 += x2.y * b1.x; a21 += x2.y * b1.y;
        a30 += x3.y * b1.x; a31 += x3.y * b1.y;
        a00 += x0.z * b2.x; a01 += x0.z * b2.y;
        a10 += x1.z * b2.x; a11 += x1.z * b2.y;
        a20 += x2.z * b2.x; a21 += x2.z * b2.y;
        a30 += x3.z * b2.x; a31 += x3.z * b2.y;
        a00 += x0.w * b3.x; a01 += x0.w * b3.y;
        a10 += x1.w * b3.x; a11 += x1.w * b3.y;
        a20 += x2.w * b3.x; a21 += x2.w * b3.y;
        a30 += x3.w * b3.x; a31 += x3.w * b3.y;
    }

    // distances -> LDS
    {
        const int j0 = 2 * t, j1 = 2 * t + 1;
        const float nj0 = norms[j0], nj1 = norms[j1];
        float dots[4][2] = {{a00, a01}, {a10, a11}, {a20, a21}, {a30, a31}};
        #pragma unroll
        for (int a = 0; a < 4; ++a) {
            const float ni = norms[i0 + a];
            float s0 = ni + nj0 - 2.0f * dots[a][0];
            float s1 = ni + nj1 - 2.0f * dots[a][1];
            drow[a][j0] = (s0 > 0.0f) ? sqrtf(s0) : 0.0f;
            drow[a][j1] = (s1 > 0.0f) ? sqrtf(s1) : 0.0f;
        }
    }
    __syncthreads();

    // ---- build positive lists ----
    #pragma unroll
    for (int a = 0; a < 4; ++a) {
        const int li = lab[i0 + a];
        int j = t;
        if (lab[j] == li && j != i0 + a) plist[a][atomicAdd(&pcnt[a], 1)] = j;
        j = t + 256;
        if (lab[j] == li && j != i0 + a) plist[a][atomicAdd(&pcnt[a], 1)] = j;
    }
    __syncthreads();

    // ---- phase 2: each thread owns negatives k = t, t+256 ----
    float lsum = 0.0f;
    unsigned int lcnt = 0;
    #pragma unroll
    for (int a = 0; a < 4; ++a) {
        const int li = lab[i0 + a];
        const int np = pcnt[a];
        const int nneg = BB - (np + 1);
        const bool n0 = (lab[t] != li);
        const bool n1 = (lab[t + 256] != li);
        const float dk0 = drow[a][t];
        const float dk1 = drow[a][t + 256];
        float s = 0.0f;
        for (int p = 0; p < np; ++p) {
            const float dj = drow[a][plist[a][p]];   // LDS broadcast
            if (n0) { float v = dj - dk0 + TMARGIN; s += (v > 0.0f) ? v : 0.0f; }
            if (n1) { float v = dj - dk1 + TMARGIN; s += (v > 0.0f) ? v : 0.0f; }
        }
        lsum += s;
        if (t == 0) lcnt += (unsigned int)np * (unsigned int)nneg;
    }

    // block reduce
    #pragma unroll
    for (int o = 32; o > 0; o >>= 1) lsum += __shfl_xor(lsum, o, 64);
    if ((t & 63) == 0) partf[t >> 6] = lsum;
    __syncthreads();
    if (t == 0) {
        atomicAdd(total, partf[0] + partf[1] + partf[2] + partf[3]);
        atomicAdd(count, lcnt);
    }
}

// ---------------- Kernel 3: finalize ----------------
__global__ void tl_finalize(const float* __restrict__ total,
                            const unsigned int* __restrict__ count,
                            float* __restrict__ out) {
    unsigned int c = *count;
    out[0] = (c > 0u) ? (*total / (float)c) : 0.0f;
}

extern "C" void kernel_launch(void* const* d_in, const int* in_sizes, int n_in,
                              void* d_out, int out_size, void* d_ws, size_t ws_size,
                              hipStream_t stream) {
    const float* X      = (const float*)d_in[0];   // [512,256] f32
    const int*   labels = (const int*)d_in[1];     // [512] int

    float*        XT    = (float*)d_ws;                               // 512 KB
    float*        norms = (float*)((char*)d_ws + 524288);             // 2 KB
    float*        total = (float*)((char*)d_ws + 526336);             // 4 B
    unsigned int* count = (unsigned int*)((char*)d_ws + 526340);      // 4 B

    hipMemsetAsync((char*)d_ws + 526336, 0, 8, stream);

    tl_transpose<<<dim3(8, 4), 256, 0, stream>>>(X, XT);
    tl_norms<<<BB, 64, 0, stream>>>(X, norms);
    tl_main<<<128, 256, 0, stream>>>(X, XT, labels, norms, total, count);
    tl_finalize<<<1, 1, 0, stream>>>(total, count, (float*)d_out);
}

// Round 3
// 36.816 us; speedup vs baseline: 2.9774x; 1.0719x over previous
//
#include <hip/hip_runtime.h>
#include <math.h>

#define BB 512
#define DD 256
#define TMARGIN 0.2f
#define NBLK 256          // 2 anchors per block
#define NTHR 512          // 1 column j per thread

// Fused kernel: distances + norms + triplet accumulation + final division.
// grid 256 x 512 threads. ws: [0]=total f32, [1]=count u32, [2]=ticket u32.
__global__ void __launch_bounds__(NTHR, 1)
tl_fused(const float* __restrict__ X,
         const int* __restrict__ labels,
         float* __restrict__ total,
         unsigned int* __restrict__ count,
         unsigned int* __restrict__ ticket,
         float* __restrict__ out) {
    __shared__ float drowL[2][520];     // [anchor][col]; slot 512 = -1e30 sentinel
    __shared__ float nrm[BB];
    __shared__ int   labL[BB];
    __shared__ int   plist[2][520];
    __shared__ int   pcnt[2];
    __shared__ float partf[8];

    const int t   = threadIdx.x;        // 0..511, also column j
    const int ia0 = blockIdx.x * 2;
    const int ia1 = ia0 + 1;

    labL[t] = labels[t];
    if (t < 2) pcnt[t] = 0;
    if (t < 16) drowL[t >> 3][512 + (t & 7)] = -1e30f;   // sentinel pads
    __syncthreads();

    // ---- build positive lists (LDS atomics; order-nondeterministic, sum is fp32-stable) ----
    {
        const int l0 = labL[ia0], l1 = labL[ia1];
        if (labL[t] == l0 && t != ia0) plist[0][atomicAdd(&pcnt[0], 1)] = t;
        if (labL[t] == l1 && t != ia1) plist[1][atomicAdd(&pcnt[1], 1)] = t;
    }

    // ---- phase 1: dot(x_a0, x_j), dot(x_a1, x_j), ||x_j||^2 for j = t ----
    float a0 = 0.f, a1 = 0.f, nn = 0.f;
    {
        const float4* xj = (const float4*)(X + (size_t)t * DD);
        const float4* xA = (const float4*)(X + (size_t)ia0 * DD);   // uniform -> s_load
        const float4* xB = (const float4*)(X + (size_t)ia1 * DD);   // uniform -> s_load
        #pragma unroll 8
        for (int g = 0; g < DD / 4; ++g) {
            const float4 b  = xj[g];
            const float4 u  = xA[g];
            const float4 v  = xB[g];
            a0 += u.x * b.x + u.y * b.y + u.z * b.z + u.w * b.w;
            a1 += v.x * b.x + v.y * b.y + v.z * b.z + v.w * b.w;
            nn += b.x * b.x + b.y * b.y + b.z * b.z + b.w * b.w;
        }
    }
    nrm[t] = nn;
    __syncthreads();    // nrm ready; plist atomics complete

    // ---- distances for this column vs both anchors ----
    float dk0, dk1;
    {
        const float ni0 = nrm[ia0], ni1 = nrm[ia1];
        float s0 = ni0 + nn - 2.0f * a0;
        float s1 = ni1 + nn - 2.0f * a1;
        dk0 = (s0 > 0.0f) ? sqrtf(s0) : 0.0f;
        dk1 = (s1 > 0.0f) ? sqrtf(s1) : 0.0f;
        drowL[0][t] = dk0;
        drowL[1][t] = dk1;
    }
    // pad positive lists to multiple of 8 with sentinel index 512
    if (t < 8) {
        int np = pcnt[0], npp = (np + 7) & ~7;
        if (t < npp - np) plist[0][np + t] = 512;
    } else if (t < 16) {
        int q = t - 8;
        int np = pcnt[1], npp = (np + 7) & ~7;
        if (q < npp - np) plist[1][np + q] = 512;
    }
    __syncthreads();

    // ---- phase 2: this thread owns negative k = t for both anchors ----
    float lsum = 0.0f;
    #pragma unroll
    for (int a = 0; a < 2; ++a) {
        const int ia = ia0 + a;
        const int li = labL[ia];
        const bool neg = (labL[t] != li);
        const float dk = (a == 0) ? dk0 : dk1;
        const int npp = (pcnt[a] + 7) & ~7;
        float s = 0.0f;
        for (int p = 0; p < npp; p += 8) {
            float dj0 = drowL[a][plist[a][p + 0]];
            float dj1 = drowL[a][plist[a][p + 1]];
            float dj2 = drowL[a][plist[a][p + 2]];
            float dj3 = drowL[a][plist[a][p + 3]];
            float dj4 = drowL[a][plist[a][p + 4]];
            float dj5 = drowL[a][plist[a][p + 5]];
            float dj6 = drowL[a][plist[a][p + 6]];
            float dj7 = drowL[a][plist[a][p + 7]];
            s += fmaxf(dj0 - dk + TMARGIN, 0.0f);
            s += fmaxf(dj1 - dk + TMARGIN, 0.0f);
            s += fmaxf(dj2 - dk + TMARGIN, 0.0f);
            s += fmaxf(dj3 - dk + TMARGIN, 0.0f);
            s += fmaxf(dj4 - dk + TMARGIN, 0.0f);
            s += fmaxf(dj5 - dk + TMARGIN, 0.0f);
            s += fmaxf(dj6 - dk + TMARGIN, 0.0f);
            s += fmaxf(dj7 - dk + TMARGIN, 0.0f);
        }
        if (neg) lsum += s;
    }

    // ---- block reduction ----
    #pragma unroll
    for (int o = 32; o > 0; o >>= 1) lsum += __shfl_xor(lsum, o, 64);
    if ((t & 63) == 0) partf[t >> 6] = lsum;
    __syncthreads();
    if (t == 0) {
        float bsum = 0.0f;
        #pragma unroll
        for (int w = 0; w < 8; ++w) bsum += partf[w];
        unsigned int bcnt = 0;
        #pragma unroll
        for (int a = 0; a < 2; ++a) {
            unsigned int np = (unsigned int)pcnt[a];
            bcnt += np * (unsigned int)(BB - 1 - np);
        }
        atomicAdd(total, bsum);
        atomicAdd(count, bcnt);
        __threadfence();
        unsigned int tk = atomicAdd(ticket, 1u);
        if (tk == (unsigned int)(NBLK - 1)) {   // last block finalizes
            float        tt = atomicAdd(total, 0.0f);   // coherent read
            unsigned int cc = atomicAdd(count, 0u);
            out[0] = (cc > 0u) ? (tt / (float)cc) : 0.0f;
        }
    }
}

extern "C" void kernel_launch(void* const* d_in, const int* in_sizes, int n_in,
                              void* d_out, int out_size, void* d_ws, size_t ws_size,
                              hipStream_t stream) {
    const float* X      = (const float*)d_in[0];   // [512,256] f32
    const int*   labels = (const int*)d_in[1];     // [512] int

    float*        total  = (float*)d_ws;
    unsigned int* count  = (unsigned int*)((char*)d_ws + 4);
    unsigned int* ticket = (unsigned int*)((char*)d_ws + 8);

    hipMemsetAsync(d_ws, 0, 12, stream);   // accumulators + ticket must start at 0 every call
    tl_fused<<<NBLK, NTHR, 0, stream>>>(X, labels, total, count, ticket, (float*)d_out);
}